// Round 1
// baseline (323.088 us; speedup 1.0000x reference)
//
#include <hip/hip_runtime.h>

#define LT_N 8192

// One wave (64 lanes) per row. Rows assigned in reverse (longest first) so
// dispatch-order ~= work-order. x staged in LDS (32 KiB) per block.
__global__ __launch_bounds__(256, 4) void tril_matvec_kernel(
    const float* __restrict__ x,
    const float* __restrict__ W,
    float* __restrict__ y)
{
    __shared__ float xs[LT_N];

    // Stage x into LDS, vectorized: 8192 floats / (256 thr * 4) = 8 iters.
    {
        const float4* x4 = (const float4*)x;
        float4* xs4 = (float4*)xs;
        for (int i = threadIdx.x; i < LT_N / 4; i += 256) xs4[i] = x4[i];
    }
    __syncthreads();

    const int wave = threadIdx.x >> 6;
    const int lane = threadIdx.x & 63;
    const int r = LT_N - 1 - (int)(blockIdx.x * 4 + wave);  // longest rows first
    const int len = r + 1;          // row r has columns [0, r]
    const int len4 = len & ~3;      // float4-covered prefix

    const float* Wr = W + (size_t)r * LT_N;

    float acc = 0.0f;
    // Main loop: lane i covers columns lane*4 + k*256, 16B aligned (row base
    // is 32KB-aligned), fully coalesced global_load_dwordx4.
    for (int j = lane * 4; j < len4; j += 64 * 4) {
        float4 w  = *(const float4*)(Wr + j);
        float4 xv = *(const float4*)(xs + j);
        acc += w.x * xv.x + w.y * xv.y + w.z * xv.z + w.w * xv.w;
    }
    // Tail: up to 3 scalar elements.
    const int rem = len - len4;
    if (lane < rem) acc += Wr[len4 + lane] * xs[len4 + lane];

    // Wave64 tree reduction.
    #pragma unroll
    for (int off = 32; off > 0; off >>= 1)
        acc += __shfl_down(acc, off, 64);

    if (lane == 0) y[r] = acc;
}

extern "C" void kernel_launch(void* const* d_in, const int* in_sizes, int n_in,
                              void* d_out, int out_size, void* d_ws, size_t ws_size,
                              hipStream_t stream)
{
    const float* x = (const float*)d_in[0];
    const float* W = (const float*)d_in[1];
    float* y = (float*)d_out;

    // 8192 rows, 4 waves (rows) per 256-thread block -> 2048 blocks.
    dim3 grid(LT_N / 4);
    dim3 block(256);
    tril_matvec_kernel<<<grid, block, 0, stream>>>(x, W, y);
}